// Round 5
// baseline (3984.430 us; speedup 1.0000x reference)
//
#include <hip/hip_runtime.h>

typedef unsigned int u32;
typedef unsigned short u16;

typedef short short8 __attribute__((ext_vector_type(8)));
typedef float f32x4 __attribute__((ext_vector_type(4)));

// ---------------- numeric helpers ----------------

__device__ __forceinline__ float fast_exp2(float x) {
#if __has_builtin(__builtin_amdgcn_exp2f)
  return __builtin_amdgcn_exp2f(x);
#else
  return exp2f(x);
#endif
}
__device__ __forceinline__ float fast_rcp(float x) {
#if __has_builtin(__builtin_amdgcn_rcpf)
  return __builtin_amdgcn_rcpf(x);
#else
  return 1.0f / x;
#endif
}
__device__ __forceinline__ float sigmf_(float x) {
  return fast_rcp(1.0f + fast_exp2(-1.44269504088896f * x));
}
__device__ __forceinline__ float tanhf_(float x) {
  float e = fast_exp2(2.88539008177793f * x);  // exp(2x)
  return 1.0f - 2.0f * fast_rcp(e + 1.0f);
}
__device__ __forceinline__ u16 f2bf(float x) {
  u32 u = __float_as_uint(x);
  u32 r = (u + 0x7fffu + ((u >> 16) & 1u)) >> 16;
  return (u16)r;
}

#if __has_builtin(__builtin_amdgcn_fdot2_f32_bf16)
typedef __bf16 bf16x2_t __attribute__((ext_vector_type(2)));
__device__ __forceinline__ float dot2bf(u32 w, u32 h, float acc) {
  return __builtin_amdgcn_fdot2_f32_bf16(__builtin_bit_cast(bf16x2_t, w),
                                         __builtin_bit_cast(bf16x2_t, h), acc, false);
}
#else
__device__ __forceinline__ float dot2bf(u32 w, u32 h, float acc) {
  float wl = __uint_as_float(w << 16);
  float wh = __uint_as_float(w & 0xffff0000u);
  float hl = __uint_as_float(h << 16);
  float hh = __uint_as_float(h & 0xffff0000u);
  return fmaf(wh, hh, fmaf(wl, hl, acc));
}
#endif

// ---------------- threefry2x32 (JAX-exact) ----------------

__device__ __forceinline__ void tf_round(u32& x0, u32& x1, int r) {
  x0 += x1;
  x1 = (x1 << r) | (x1 >> (32 - r));
  x1 ^= x0;
}
__device__ void threefry(u32 k0, u32 k1, u32 c0, u32 c1, u32& o0, u32& o1) {
  u32 k2 = k0 ^ k1 ^ 0x1BD11BDAu;
  u32 x0 = c0 + k0, x1 = c1 + k1;
  tf_round(x0, x1, 13); tf_round(x0, x1, 15); tf_round(x0, x1, 26); tf_round(x0, x1, 6);
  x0 += k1; x1 += k2 + 1u;
  tf_round(x0, x1, 17); tf_round(x0, x1, 29); tf_round(x0, x1, 16); tf_round(x0, x1, 24);
  x0 += k2; x1 += k0 + 2u;
  tf_round(x0, x1, 13); tf_round(x0, x1, 15); tf_round(x0, x1, 26); tf_round(x0, x1, 6);
  x0 += k0; x1 += k1 + 3u;
  tf_round(x0, x1, 17); tf_round(x0, x1, 29); tf_round(x0, x1, 16); tf_round(x0, x1, 24);
  x0 += k1; x1 += k2 + 4u;
  tf_round(x0, x1, 13); tf_round(x0, x1, 15); tf_round(x0, x1, 26); tf_round(x0, x1, 6);
  x0 += k2; x1 += k0 + 5u;
  o0 = x0; o1 = x1;
}

#define JAX_PARTITIONABLE 1

// masks layout: [layer(2)][type(3: out,h,c)][b*256+h (16384)]
__global__ void masks_kernel(float* __restrict__ masks) {
  int gid = blockIdx.x * 256 + threadIdx.x;
  if (gid >= 2 * 3 * 16384) return;
  int l = gid / 49152;
  int rem = gid - l * 49152;
  int typ = rem / 16384;
  int i = rem - typ * 16384;
  u32 bits;
#if JAX_PARTITIONABLE
  u32 lk0, lk1, mk0, mk1, y0, y1;
  threefry(0u, 42u, 0u, (u32)l, lk0, lk1);
  threefry(lk0, lk1, 0u, (u32)typ, mk0, mk1);
  threefry(mk0, mk1, 0u, (u32)i, y0, y1);
  bits = y0 ^ y1;
#else
  u32 a0, a1, b0, b1;
  threefry(0u, 42u, 0u, 2u, a0, a1);
  threefry(0u, 42u, 1u, 3u, b0, b1);
  u32 lk0 = (l == 0) ? a0 : a1;
  u32 lk1 = (l == 0) ? b0 : b1;
  u32 e00, e01, e10, e11, e20, e21;
  threefry(lk0, lk1, 0u, 3u, e00, e01);
  threefry(lk0, lk1, 1u, 4u, e10, e11);
  threefry(lk0, lk1, 2u, 5u, e20, e21);
  u32 mk0 = (typ == 0) ? e00 : (typ == 1) ? e20 : e11;
  u32 mk1 = (typ == 0) ? e10 : (typ == 1) ? e01 : e21;
  u32 p = (i < 8192) ? (u32)i : (u32)(i - 8192);
  u32 y0, y1;
  threefry(mk0, mk1, p, p + 8192u, y0, y1);
  bits = (i < 8192) ? y0 : y1;
#endif
  float u = __uint_as_float((bits >> 9) | 0x3f800000u) - 1.0f;
  masks[gid] = (u < 0.75f) ? (1.0f / 0.75f) : 0.0f;
}

// ---------------- prep kernels ----------------

__global__ void conv_bf16(const float* __restrict__ src, u16* __restrict__ dst, int n) {
  int gid = blockIdx.x * 256 + threadIdx.x;
  if (gid < n) dst[gid] = f2bf(src[gid]);
}

// W_hh [1024 rows][256 cols] f32 -> Wq [32 chunks][1024 rows] of uint4,
// chunk q of row r = bf16x2 pairs (4q..4q+3), i.e. cols 8q..8q+7.
__global__ void pack_whh(const float* __restrict__ W, u32* __restrict__ Wq) {
  int gid = blockIdx.x * 256 + threadIdx.x;  // 131072 = 128 pairs * 1024 rows
  int p = gid >> 10;
  int row = gid & 1023;
  u32 lo = f2bf(W[row * 256 + 2 * p]);
  u32 hi = f2bf(W[row * 256 + 2 * p + 1]);
  u32 v = lo | (hi << 16);
  int q = p >> 2, e = p & 3;
  Wq[(q * 1024 + row) * 4 + e] = v;
}

__global__ void add_bias(const float* __restrict__ a, const float* __restrict__ b,
                         float* __restrict__ o, int n) {
  int gid = blockIdx.x * 256 + threadIdx.x;
  if (gid < n) o[gid] = a[gid] + b[gid];
}

// ---------------- input-projection GEMM (bf16 MFMA) ----------------
__global__ __launch_bounds__(256) void gemm_xg(const u16* __restrict__ A,
                                               const u16* __restrict__ Bw,
                                               float* __restrict__ xg) {
  __shared__ uint4 Als[2048];
  __shared__ uint4 Bls[2048];
  int tid = threadIdx.x;
  int m0 = blockIdx.x * 64;
  int n0 = blockIdx.y * 64;
  {
    int row = tid >> 2, kseg = tid & 3;
    const uint4* Ag = (const uint4*)(A + (size_t)(m0 + row) * 256);
    const uint4* Bg = (const uint4*)(Bw + (size_t)(n0 + row) * 256);
#pragma unroll
    for (int uu = 0; uu < 8; ++uu) {
      int kb = kseg * 8 + uu;
      Als[kb * 64 + row] = Ag[kb];
      Bls[kb * 64 + row] = Bg[kb];
    }
  }
  __syncthreads();
  int w = tid >> 6, l = tid & 63;
  int wm = (w >> 1) * 32, wn = (w & 1) * 32;
  int lm = l & 15, q = l >> 4;
  f32x4 acc00 = {0.f, 0.f, 0.f, 0.f}, acc01 = acc00, acc10 = acc00, acc11 = acc00;
#pragma unroll
  for (int ks = 0; ks < 8; ++ks) {
    int kb = ks * 4 + q;
    short8 a0 = __builtin_bit_cast(short8, Als[kb * 64 + wm + lm]);
    short8 a1 = __builtin_bit_cast(short8, Als[kb * 64 + wm + 16 + lm]);
    short8 b0 = __builtin_bit_cast(short8, Bls[kb * 64 + wn + lm]);
    short8 b1 = __builtin_bit_cast(short8, Bls[kb * 64 + wn + 16 + lm]);
    acc00 = __builtin_amdgcn_mfma_f32_16x16x32_bf16(a0, b0, acc00, 0, 0, 0);
    acc01 = __builtin_amdgcn_mfma_f32_16x16x32_bf16(a0, b1, acc01, 0, 0, 0);
    acc10 = __builtin_amdgcn_mfma_f32_16x16x32_bf16(a1, b0, acc10, 0, 0, 0);
    acc11 = __builtin_amdgcn_mfma_f32_16x16x32_bf16(a1, b1, acc11, 0, 0, 0);
  }
#pragma unroll
  for (int fm = 0; fm < 2; ++fm)
#pragma unroll
    for (int fn = 0; fn < 2; ++fn) {
      f32x4 acc = (fm == 0) ? ((fn == 0) ? acc00 : acc01) : ((fn == 0) ? acc10 : acc11);
#pragma unroll
      for (int r = 0; r < 4; ++r) {
        int m = m0 + wm + fm * 16 + q * 4 + r;
        int n = n0 + wn + fn * 16 + lm;
        int bb = m >> 9, tt = m & 511;
        xg[(size_t)tt * 65536 + (size_t)bb * 1024 + n] = acc[r];
      }
    }
}

// ---------------- persistent recurrence v5 ----------------
// One WG (512 threads = 8 waves, 2/SIMD) per batch element.
// amdgpu_waves_per_eu(2,2) pins occupancy at exactly 2 waves/SIMD so the
// register allocator gets the full 512/2 = 256-VGPR budget (launch_bounds'
// 2nd arg alone is a MINIMUM: the compiler doubled occupancy and halved the
// budget in R3/R4, spilling the W array to scratch -> VGPR_Count 64/128).
// W chunks 0..RCH-1 register-resident (2 rows x RCH uint4 = 160 VGPRs);
// chunks RCH..31 streamed from per-XCD L2 with a 4-deep rolling prefetch.
#define RCH 20
#define SCH (32 - RCH)

__global__ __launch_bounds__(512)
__attribute__((amdgpu_waves_per_eu(2, 2))) void lstm_rec(
    const uint4* __restrict__ Wq,    // [32][1024] chunk-major
    const float* __restrict__ xg,    // [512][64][1024]
    const float* __restrict__ bias,  // [1024] (b_ih + b_hh)
    const float* __restrict__ masks, // [3][16384] this layer (out,h,c)
    float* __restrict__ outF,        // layer2: d_out [64][512][256], else null
    u16* __restrict__ outB)          // layer1: bf16 out for next GEMM, else null
{
  __shared__ float gates[1024];
  __shared__ alignas(16) u16 hbf[256];

  const int tid = threadIdx.x;
  const int b = blockIdx.x;
  const int r0 = tid, r1 = tid + 512;

  uint4 wreg[2][RCH];
#pragma unroll
  for (int cc = 0; cc < RCH; ++cc) {
    wreg[0][cc] = Wq[cc * 1024 + r0];
    wreg[1][cc] = Wq[cc * 1024 + r1];
  }

  if (tid < 256) hbf[tid] = 0;

  const float bias0 = bias[r0];
  const float bias1 = bias[r1];
  float c = 0.f, m_out = 0.f, m_h = 0.f, m_c = 0.f;
  if (tid < 256) {
    m_out = masks[0 * 16384 + b * 256 + tid];
    m_h   = masks[1 * 16384 + b * 256 + tid];
    m_c   = masks[2 * 16384 + b * 256 + tid];
  }

  const float* xgp = xg + b * 1024;
  float* outFp = outF ? outF + (size_t)b * 512 * 256 + tid : (float*)0;
  u16* outBp = outB ? outB + (size_t)b * 512 * 256 + tid : (u16*)0;

  float xgc0 = xgp[r0];  // t=0 prefetch
  float xgc1 = xgp[r1];
  __syncthreads();

#pragma unroll 1
  for (int t = 0; t < 512; ++t) {
    // prefetch xg for t+1 (consumed next iter; in flight for a full step)
    float xgn0 = 0.f, xgn1 = 0.f;
    if (t < 511) {
      xgn0 = xgp[(size_t)(t + 1) * 65536 + r0];
      xgn1 = xgp[(size_t)(t + 1) * 65536 + r1];
    }

    // issue first 4 streamed W chunks (ready after the register dot-loop)
    uint4 tb[4][2];
#pragma unroll
    for (int j = 0; j < 4; ++j) {
      tb[j][0] = Wq[(RCH + j) * 1024 + r0];
      tb[j][1] = Wq[(RCH + j) * 1024 + r1];
    }

    const uint4* h4 = (const uint4*)hbf;
    float acc0 = bias0, acc1 = bias1;
    uint4 hp = h4[0];

    // register-resident part: chunks 0..RCH-1
#pragma unroll
    for (int cc = 0; cc < RCH; ++cc) {
      uint4 hc = hp;
      hp = h4[cc + 1];  // cc+1 <= RCH <= 31: always valid
      acc0 = dot2bf(wreg[0][cc].x, hc.x, acc0);
      acc1 = dot2bf(wreg[1][cc].x, hc.x, acc1);
      acc0 = dot2bf(wreg[0][cc].y, hc.y, acc0);
      acc1 = dot2bf(wreg[1][cc].y, hc.y, acc1);
      acc0 = dot2bf(wreg[0][cc].z, hc.z, acc0);
      acc1 = dot2bf(wreg[1][cc].z, hc.z, acc1);
      acc0 = dot2bf(wreg[0][cc].w, hc.w, acc0);
      acc1 = dot2bf(wreg[1][cc].w, hc.w, acc1);
    }

    // streamed part: chunks RCH..31, 4-deep rolling prefetch
#pragma unroll
    for (int j = 0; j < SCH; ++j) {
      uint4 c0 = tb[j & 3][0];
      uint4 c1 = tb[j & 3][1];
      if (j + 4 < SCH) {
        tb[j & 3][0] = Wq[(RCH + 4 + j) * 1024 + r0];
        tb[j & 3][1] = Wq[(RCH + 4 + j) * 1024 + r1];
      }
      uint4 hc = hp;
      if (RCH + j + 1 < 32) hp = h4[RCH + j + 1];
      acc0 = dot2bf(c0.x, hc.x, acc0);
      acc1 = dot2bf(c1.x, hc.x, acc1);
      acc0 = dot2bf(c0.y, hc.y, acc0);
      acc1 = dot2bf(c1.y, hc.y, acc1);
      acc0 = dot2bf(c0.z, hc.z, acc0);
      acc1 = dot2bf(c1.z, hc.z, acc1);
      acc0 = dot2bf(c0.w, hc.w, acc0);
      acc1 = dot2bf(c1.w, hc.w, acc1);
    }

    gates[r0] = acc0 + xgc0;
    gates[r1] = acc1 + xgc1;
    __syncthreads();

    if (tid < 256) {
      float gi = gates[tid];
      float gf = gates[tid + 256];
      float gg = gates[tid + 512];
      float go = gates[tid + 768];
      float fi = sigmf_(gi), ff = sigmf_(gf), fo = sigmf_(go);
      float tg = tanhf_(gg);
      c = ff * c + fi * tg;
      float hn = fo * tanhf_(c);
      float ov = hn * m_out;
      if (outFp) outFp[t * 256] = ov;
      if (outBp) outBp[t * 256] = f2bf(ov);
      hbf[tid] = f2bf(hn * m_h);  // variational h-mask on carry
      c *= m_c;                   // c-mask on carry
    }
    __syncthreads();

    xgc0 = xgn0;
    xgc1 = xgn1;
  }
}

// ---------------- launch ----------------

extern "C" void kernel_launch(void* const* d_in, const int* in_sizes, int n_in,
                              void* d_out, int out_size, void* d_ws, size_t ws_size,
                              hipStream_t stream) {
  const float* x    = (const float*)d_in[0];
  const float* Wih0 = (const float*)d_in[1];
  const float* Whh0 = (const float*)d_in[2];
  const float* bih0 = (const float*)d_in[3];
  const float* bhh0 = (const float*)d_in[4];
  const float* Wih1 = (const float*)d_in[5];
  const float* Whh1 = (const float*)d_in[6];
  const float* bih1 = (const float*)d_in[7];
  const float* bhh1 = (const float*)d_in[8];
  float* out = (float*)d_out;

  char* w = (char*)d_ws;
  float* masks = (float*)(w + 0);             // 393216 B
  float* biasb = (float*)(w + 393216);        // 8192 B
  u32* Wq0     = (u32*)(w + 401408);          // 524288 B  (32*1024*16)
  u32* Wq1     = (u32*)(w + 925696);          // 524288 B
  u16* Wih0b   = (u16*)(w + 1449984);         // 524288 B
  u16* Wih1b   = (u16*)(w + 1974272);         // 524288 B
  u16* xb      = (u16*)(w + 2498560);         // 16777216 B
  u16* o1b     = (u16*)(w + 19275776);        // 16777216 B
  float* xg    = (float*)(w + 36052992);      // 134217728 B (total ~170.3 MB)

  hipLaunchKernelGGL(masks_kernel, dim3(384), dim3(256), 0, stream, masks);
  hipLaunchKernelGGL(conv_bf16, dim3(32768), dim3(256), 0, stream, x, xb, 8388608);
  hipLaunchKernelGGL(conv_bf16, dim3(1024), dim3(256), 0, stream, Wih0, Wih0b, 262144);
  hipLaunchKernelGGL(conv_bf16, dim3(1024), dim3(256), 0, stream, Wih1, Wih1b, 262144);
  hipLaunchKernelGGL(pack_whh, dim3(512), dim3(256), 0, stream, Whh0, Wq0);
  hipLaunchKernelGGL(pack_whh, dim3(512), dim3(256), 0, stream, Whh1, Wq1);
  hipLaunchKernelGGL(add_bias, dim3(4), dim3(256), 0, stream, bih0, bhh0, biasb, 1024);
  hipLaunchKernelGGL(add_bias, dim3(4), dim3(256), 0, stream, bih1, bhh1, biasb + 1024, 1024);

  // layer 1
  hipLaunchKernelGGL(gemm_xg, dim3(512, 16), dim3(256), 0, stream, xb, Wih0b, xg);
  hipLaunchKernelGGL(lstm_rec, dim3(64), dim3(512), 0, stream, (const uint4*)Wq0, xg,
                     biasb, masks, (float*)nullptr, o1b);
  // layer 2
  hipLaunchKernelGGL(gemm_xg, dim3(512, 16), dim3(256), 0, stream, o1b, Wih1b, xg);
  hipLaunchKernelGGL(lstm_rec, dim3(64), dim3(512), 0, stream, (const uint4*)Wq1, xg,
                     biasb + 1024, masks + 49152, out, (u16*)nullptr);
}

// Round 6
// 2603.738 us; speedup vs baseline: 1.5303x; 1.5303x over previous
//
#include <hip/hip_runtime.h>

typedef unsigned int u32;
typedef unsigned short u16;

typedef short short8 __attribute__((ext_vector_type(8)));
typedef float f32x4 __attribute__((ext_vector_type(4)));

// ---------------- numeric helpers ----------------

__device__ __forceinline__ float fast_exp2(float x) {
#if __has_builtin(__builtin_amdgcn_exp2f)
  return __builtin_amdgcn_exp2f(x);
#else
  return exp2f(x);
#endif
}
__device__ __forceinline__ float fast_rcp(float x) {
#if __has_builtin(__builtin_amdgcn_rcpf)
  return __builtin_amdgcn_rcpf(x);
#else
  return 1.0f / x;
#endif
}
__device__ __forceinline__ float sigmf_(float x) {
  return fast_rcp(1.0f + fast_exp2(-1.44269504088896f * x));
}
__device__ __forceinline__ float tanhf_(float x) {
  float e = fast_exp2(2.88539008177793f * x);  // exp(2x)
  return 1.0f - 2.0f * fast_rcp(e + 1.0f);
}
__device__ __forceinline__ u16 f2bf(float x) {
  u32 u = __float_as_uint(x);
  u32 r = (u + 0x7fffu + ((u >> 16) & 1u)) >> 16;
  return (u16)r;
}

#if __has_builtin(__builtin_amdgcn_fdot2_f32_bf16)
typedef __bf16 bf16x2_t __attribute__((ext_vector_type(2)));
__device__ __forceinline__ float dot2bf(u32 w, u32 h, float acc) {
  return __builtin_amdgcn_fdot2_f32_bf16(__builtin_bit_cast(bf16x2_t, w),
                                         __builtin_bit_cast(bf16x2_t, h), acc, false);
}
#else
__device__ __forceinline__ float dot2bf(u32 w, u32 h, float acc) {
  float wl = __uint_as_float(w << 16);
  float wh = __uint_as_float(w & 0xffff0000u);
  float hl = __uint_as_float(h << 16);
  float hh = __uint_as_float(h & 0xffff0000u);
  return fmaf(wh, hh, fmaf(wl, hl, acc));
}
#endif

// ---------------- threefry2x32 (JAX-exact) ----------------

__device__ __forceinline__ void tf_round(u32& x0, u32& x1, int r) {
  x0 += x1;
  x1 = (x1 << r) | (x1 >> (32 - r));
  x1 ^= x0;
}
__device__ void threefry(u32 k0, u32 k1, u32 c0, u32 c1, u32& o0, u32& o1) {
  u32 k2 = k0 ^ k1 ^ 0x1BD11BDAu;
  u32 x0 = c0 + k0, x1 = c1 + k1;
  tf_round(x0, x1, 13); tf_round(x0, x1, 15); tf_round(x0, x1, 26); tf_round(x0, x1, 6);
  x0 += k1; x1 += k2 + 1u;
  tf_round(x0, x1, 17); tf_round(x0, x1, 29); tf_round(x0, x1, 16); tf_round(x0, x1, 24);
  x0 += k2; x1 += k0 + 2u;
  tf_round(x0, x1, 13); tf_round(x0, x1, 15); tf_round(x0, x1, 26); tf_round(x0, x1, 6);
  x0 += k0; x1 += k1 + 3u;
  tf_round(x0, x1, 17); tf_round(x0, x1, 29); tf_round(x0, x1, 16); tf_round(x0, x1, 24);
  x0 += k1; x1 += k2 + 4u;
  tf_round(x0, x1, 13); tf_round(x0, x1, 15); tf_round(x0, x1, 26); tf_round(x0, x1, 6);
  x0 += k2; x1 += k0 + 5u;
  o0 = x0; o1 = x1;
}

#define JAX_PARTITIONABLE 1

// masks layout: [layer(2)][type(3: out,h,c)][b*256+h (16384)]
__global__ void masks_kernel(float* __restrict__ masks) {
  int gid = blockIdx.x * 256 + threadIdx.x;
  if (gid >= 2 * 3 * 16384) return;
  int l = gid / 49152;
  int rem = gid - l * 49152;
  int typ = rem / 16384;
  int i = rem - typ * 16384;
  u32 bits;
#if JAX_PARTITIONABLE
  u32 lk0, lk1, mk0, mk1, y0, y1;
  threefry(0u, 42u, 0u, (u32)l, lk0, lk1);
  threefry(lk0, lk1, 0u, (u32)typ, mk0, mk1);
  threefry(mk0, mk1, 0u, (u32)i, y0, y1);
  bits = y0 ^ y1;
#else
  u32 a0, a1, b0, b1;
  threefry(0u, 42u, 0u, 2u, a0, a1);
  threefry(0u, 42u, 1u, 3u, b0, b1);
  u32 lk0 = (l == 0) ? a0 : a1;
  u32 lk1 = (l == 0) ? b0 : b1;
  u32 e00, e01, e10, e11, e20, e21;
  threefry(lk0, lk1, 0u, 3u, e00, e01);
  threefry(lk0, lk1, 1u, 4u, e10, e11);
  threefry(lk0, lk1, 2u, 5u, e20, e21);
  u32 mk0 = (typ == 0) ? e00 : (typ == 1) ? e20 : e11;
  u32 mk1 = (typ == 0) ? e10 : (typ == 1) ? e01 : e21;
  u32 p = (i < 8192) ? (u32)i : (u32)(i - 8192);
  u32 y0, y1;
  threefry(mk0, mk1, p, p + 8192u, y0, y1);
  bits = (i < 8192) ? y0 : y1;
#endif
  float u = __uint_as_float((bits >> 9) | 0x3f800000u) - 1.0f;
  masks[gid] = (u < 0.75f) ? (1.0f / 0.75f) : 0.0f;
}

// ---------------- prep kernels ----------------

__global__ void conv_bf16(const float* __restrict__ src, u16* __restrict__ dst, int n) {
  int gid = blockIdx.x * 256 + threadIdx.x;
  if (gid < n) dst[gid] = f2bf(src[gid]);
}

// W_hh [1024 rows][256 cols] f32 -> Wt [j 0..63][tid 0..511] uint4 (bf16x2 x4).
// lstm thread tid: rg=tid>>1, half=tid&1 owns rows {rg,rg+256,rg+512,rg+768}
// over K-half `half`. j = kc*4 + r, kc in [0,16): value = row rg+256r,
// cols 8*(16*half+kc) .. +7.
__global__ void pack_whh(const float* __restrict__ W, u32* __restrict__ Wt) {
  int gid = blockIdx.x * 256 + threadIdx.x;  // 131072 u32 total
  int e = gid & 3;
  int tid = (gid >> 2) & 511;
  int j = gid >> 11;  // 0..63
  int rg = tid >> 1, half = tid & 1;
  int r = j & 3, kc = j >> 2;
  int row = rg + 256 * r;
  int col0 = 8 * (16 * half + kc) + 2 * e;
  u32 lo = f2bf(W[row * 256 + col0]);
  u32 hi = f2bf(W[row * 256 + col0 + 1]);
  Wt[(j * 512 + tid) * 4 + e] = lo | (hi << 16);
}

__global__ void add_bias(const float* __restrict__ a, const float* __restrict__ b,
                         float* __restrict__ o, int n) {
  int gid = blockIdx.x * 256 + threadIdx.x;
  if (gid < n) o[gid] = a[gid] + b[gid];
}

// ---------------- input-projection GEMM (bf16 MFMA, bias fused) ----------------
__global__ __launch_bounds__(256) void gemm_xg(const u16* __restrict__ A,
                                               const u16* __restrict__ Bw,
                                               const float* __restrict__ bias,
                                               float* __restrict__ xg) {
  __shared__ uint4 Als[2048];
  __shared__ uint4 Bls[2048];
  int tid = threadIdx.x;
  int m0 = blockIdx.x * 64;
  int n0 = blockIdx.y * 64;
  {
    int row = tid >> 2, kseg = tid & 3;
    const uint4* Ag = (const uint4*)(A + (size_t)(m0 + row) * 256);
    const uint4* Bg = (const uint4*)(Bw + (size_t)(n0 + row) * 256);
#pragma unroll
    for (int uu = 0; uu < 8; ++uu) {
      int kb = kseg * 8 + uu;
      Als[kb * 64 + row] = Ag[kb];
      Bls[kb * 64 + row] = Bg[kb];
    }
  }
  __syncthreads();
  int w = tid >> 6, l = tid & 63;
  int wm = (w >> 1) * 32, wn = (w & 1) * 32;
  int lm = l & 15, q = l >> 4;
  f32x4 acc00 = {0.f, 0.f, 0.f, 0.f}, acc01 = acc00, acc10 = acc00, acc11 = acc00;
#pragma unroll
  for (int ks = 0; ks < 8; ++ks) {
    int kb = ks * 4 + q;
    short8 a0 = __builtin_bit_cast(short8, Als[kb * 64 + wm + lm]);
    short8 a1 = __builtin_bit_cast(short8, Als[kb * 64 + wm + 16 + lm]);
    short8 b0 = __builtin_bit_cast(short8, Bls[kb * 64 + wn + lm]);
    short8 b1 = __builtin_bit_cast(short8, Bls[kb * 64 + wn + 16 + lm]);
    acc00 = __builtin_amdgcn_mfma_f32_16x16x32_bf16(a0, b0, acc00, 0, 0, 0);
    acc01 = __builtin_amdgcn_mfma_f32_16x16x32_bf16(a0, b1, acc01, 0, 0, 0);
    acc10 = __builtin_amdgcn_mfma_f32_16x16x32_bf16(a1, b0, acc10, 0, 0, 0);
    acc11 = __builtin_amdgcn_mfma_f32_16x16x32_bf16(a1, b1, acc11, 0, 0, 0);
  }
#pragma unroll
  for (int fm = 0; fm < 2; ++fm)
#pragma unroll
    for (int fn = 0; fn < 2; ++fn) {
      f32x4 acc = (fm == 0) ? ((fn == 0) ? acc00 : acc01) : ((fn == 0) ? acc10 : acc11);
      int n = n0 + wn + fn * 16 + lm;
      float bv = bias[n];
#pragma unroll
      for (int r = 0; r < 4; ++r) {
        int m = m0 + wm + fm * 16 + q * 4 + r;
        int bb = m >> 9, tt = m & 511;
        xg[(size_t)tt * 65536 + (size_t)bb * 1024 + n] = acc[r] + bv;
      }
    }
}

// ---------------- persistent recurrence v6 ----------------
// One WG (512 threads, 8 waves, 2/SIMD) per batch element.
// Thread (rg=tid>>1, half=tid&1) owns gate rows {rg,+256,+512,+768} over
// K-half `half` (split-K): halves combined by one shfl_xor(1) per gate, so
// gates never touch LDS and there is ONE barrier per step.
// W per thread = 64 uint4: NA in arch VGPRs, NG in AGPRs (inline-asm "a"
// class — the only way past the 128-arch-VGPR allocator cap observed in
// R1-R5), NL in LDS, NS streamed from per-XCD L2 (rolling prefetch).
#define NA 16
#define NG 30
#define NL 7
#define NS 11
// boundaries: arch j<16, agpr 16<=j<46, lds 46<=j<53, stream 53<=j<64

__global__ __launch_bounds__(512)
__attribute__((amdgpu_waves_per_eu(2, 2))) void lstm_rec(
    const uint4* __restrict__ Wt4,   // [64][512] per-thread chunks
    const float* __restrict__ xg,    // [512][64][1024] (bias pre-added)
    const float* __restrict__ masks, // [3][16384] this layer (out,h,c)
    float* __restrict__ outF,        // layer2: d_out [64][512][256], else null
    u16* __restrict__ outB)          // layer1: bf16 out for next GEMM, else null
{
  __shared__ alignas(16) uint4 Wl[NL * 512];
  __shared__ alignas(16) u16 hbf[2][256];

  const int tid = threadIdx.x;
  const int b = blockIdx.x;
  const int rg = tid >> 1, half = tid & 1;

  // arch-VGPR W
  uint4 warch[NA];
#pragma unroll
  for (int j = 0; j < NA; ++j) warch[j] = Wt4[j * 512 + tid];

  // AGPR W (def/use pinned to AGPR class via asm constraints)
  u32 wag[NG * 4];
#pragma unroll
  for (int j = NA; j < NA + NG; ++j) {
    uint4 t = Wt4[j * 512 + tid];
    asm volatile("v_accvgpr_write_b32 %0, %1" : "=a"(wag[(j - NA) * 4 + 0]) : "v"(t.x));
    asm volatile("v_accvgpr_write_b32 %0, %1" : "=a"(wag[(j - NA) * 4 + 1]) : "v"(t.y));
    asm volatile("v_accvgpr_write_b32 %0, %1" : "=a"(wag[(j - NA) * 4 + 2]) : "v"(t.z));
    asm volatile("v_accvgpr_write_b32 %0, %1" : "=a"(wag[(j - NA) * 4 + 3]) : "v"(t.w));
  }

  // LDS W
#pragma unroll
  for (int j = NA + NG; j < NA + NG + NL; ++j)
    Wl[(j - NA - NG) * 512 + tid] = Wt4[j * 512 + tid];

  float m_out = 0.f, m_h = 0.f, m_c = 0.f, c = 0.f;
  if (half == 0) {
    m_out = masks[0 * 16384 + b * 256 + rg];
    m_h   = masks[1 * 16384 + b * 256 + rg];
    m_c   = masks[2 * 16384 + b * 256 + rg];
    hbf[0][rg] = 0;
  }

  const float* xgp = xg + b * 1024;
  float* outFp = outF ? outF + (size_t)b * 512 * 256 + rg : (float*)0;
  u16* outBp = outB ? outB + (size_t)b * 512 * 256 + rg : (u16*)0;

  __syncthreads();

#pragma unroll 1
  for (int t = 0; t < 512; ++t) {
    // xg for this step (L3/L2-resident; ~1500 cyc of dot2 hides the latency)
    float xgv[4] = {0.f, 0.f, 0.f, 0.f};
    if (half == 0) {
#pragma unroll
      for (int r = 0; r < 4; ++r) xgv[r] = xgp[(size_t)t * 65536 + rg + 256 * r];
    }

    // rolling prefetch of streamed W chunks (L2-hot, same addrs every step)
    uint4 tb[4];
#pragma unroll
    for (int j = 0; j < 4; ++j) tb[j] = Wt4[(NA + NG + NL + j) * 512 + tid];

    const uint4* h4 = (const uint4*)hbf[t & 1];
    float acc[4] = {0.f, 0.f, 0.f, 0.f};

#pragma unroll
    for (int kc = 0; kc < 16; ++kc) {
      uint4 hp = h4[16 * half + kc];
#pragma unroll
      for (int r = 0; r < 4; ++r) {
        const int j = kc * 4 + r;
        uint4 wv;
        if (j < NA) {
          wv = warch[j];
        } else if (j < NA + NG) {
          asm volatile("v_accvgpr_read_b32 %0, %1" : "=v"(wv.x) : "a"(wag[(j - NA) * 4 + 0]));
          asm volatile("v_accvgpr_read_b32 %0, %1" : "=v"(wv.y) : "a"(wag[(j - NA) * 4 + 1]));
          asm volatile("v_accvgpr_read_b32 %0, %1" : "=v"(wv.z) : "a"(wag[(j - NA) * 4 + 2]));
          asm volatile("v_accvgpr_read_b32 %0, %1" : "=v"(wv.w) : "a"(wag[(j - NA) * 4 + 3]));
        } else if (j < NA + NG + NL) {
          wv = Wl[(j - NA - NG) * 512 + tid];
        } else {
          const int s = j - (NA + NG + NL);
          wv = tb[s & 3];
          if (s + 4 < NS) tb[s & 3] = Wt4[(j + 4) * 512 + tid];
        }
        acc[r] = dot2bf(wv.x, hp.x, acc[r]);
        acc[r] = dot2bf(wv.y, hp.y, acc[r]);
        acc[r] = dot2bf(wv.z, hp.z, acc[r]);
        acc[r] = dot2bf(wv.w, hp.w, acc[r]);
      }
    }

    // combine K-halves: partner is lane^1 (tid^1, same 4 rows)
#pragma unroll
    for (int r = 0; r < 4; ++r) acc[r] += __shfl_xor(acc[r], 1);

    if (half == 0) {
      float gi = acc[0] + xgv[0];
      float gf = acc[1] + xgv[1];
      float gg = acc[2] + xgv[2];
      float go = acc[3] + xgv[3];
      float fi = sigmf_(gi), ff = sigmf_(gf), fo = sigmf_(go);
      float tg = tanhf_(gg);
      c = ff * c + fi * tg;
      float hn = fo * tanhf_(c);
      float ov = hn * m_out;
      if (outFp) outFp[t * 256] = ov;
      if (outBp) outBp[t * 256] = f2bf(ov);
      hbf[(t + 1) & 1][rg] = f2bf(hn * m_h);  // variational h-mask on carry
      c *= m_c;                               // c-mask on carry
    }
    __syncthreads();
  }
}

// ---------------- launch ----------------

extern "C" void kernel_launch(void* const* d_in, const int* in_sizes, int n_in,
                              void* d_out, int out_size, void* d_ws, size_t ws_size,
                              hipStream_t stream) {
  const float* x    = (const float*)d_in[0];
  const float* Wih0 = (const float*)d_in[1];
  const float* Whh0 = (const float*)d_in[2];
  const float* bih0 = (const float*)d_in[3];
  const float* bhh0 = (const float*)d_in[4];
  const float* Wih1 = (const float*)d_in[5];
  const float* Whh1 = (const float*)d_in[6];
  const float* bih1 = (const float*)d_in[7];
  const float* bhh1 = (const float*)d_in[8];
  float* out = (float*)d_out;

  char* w = (char*)d_ws;
  float* masks = (float*)(w + 0);             // 393216 B
  float* biasb = (float*)(w + 393216);        // 8192 B
  u32* Wt0     = (u32*)(w + 401408);          // 524288 B  (64*512*16)
  u32* Wt1     = (u32*)(w + 925696);          // 524288 B
  u16* Wih0b   = (u16*)(w + 1449984);         // 524288 B
  u16* Wih1b   = (u16*)(w + 1974272);         // 524288 B
  u16* xb      = (u16*)(w + 2498560);         // 16777216 B
  u16* o1b     = (u16*)(w + 19275776);        // 16777216 B
  float* xg    = (float*)(w + 36052992);      // 134217728 B (total ~170.3 MB)

  hipLaunchKernelGGL(masks_kernel, dim3(384), dim3(256), 0, stream, masks);
  hipLaunchKernelGGL(conv_bf16, dim3(32768), dim3(256), 0, stream, x, xb, 8388608);
  hipLaunchKernelGGL(conv_bf16, dim3(1024), dim3(256), 0, stream, Wih0, Wih0b, 262144);
  hipLaunchKernelGGL(conv_bf16, dim3(1024), dim3(256), 0, stream, Wih1, Wih1b, 262144);
  hipLaunchKernelGGL(pack_whh, dim3(512), dim3(256), 0, stream, Whh0, Wt0);
  hipLaunchKernelGGL(pack_whh, dim3(512), dim3(256), 0, stream, Whh1, Wt1);
  hipLaunchKernelGGL(add_bias, dim3(4), dim3(256), 0, stream, bih0, bhh0, biasb, 1024);
  hipLaunchKernelGGL(add_bias, dim3(4), dim3(256), 0, stream, bih1, bhh1, biasb + 1024, 1024);

  // layer 1
  hipLaunchKernelGGL(gemm_xg, dim3(512, 16), dim3(256), 0, stream, xb, Wih0b, biasb, xg);
  hipLaunchKernelGGL(lstm_rec, dim3(64), dim3(512), 0, stream, (const uint4*)Wt0, xg,
                     masks, (float*)nullptr, o1b);
  // layer 2
  hipLaunchKernelGGL(gemm_xg, dim3(512, 16), dim3(256), 0, stream, o1b, Wih1b, biasb + 1024, xg);
  hipLaunchKernelGGL(lstm_rec, dim3(64), dim3(512), 0, stream, (const uint4*)Wt1, xg,
                     masks + 49152, out, (u16*)nullptr);
}